// Round 1
// baseline (2768.340 us; speedup 1.0000x reference)
//
#include <hip/hip_runtime.h>
#include <hip/hip_fp16.h>

// Bidirectional GRU: T=512, B=512, I=100, H=96, gate order (r,z,n).
// Plan:
//   proj_kernel: xp[dir][m][g] = x_row . W_ih[g] + b_ih[g], fp16 in d_ws.
//                dir=1 stored time-reversed so scan reads sequentially.
//   scan_kernel: 2x512 independent recurrence chains; block = 288 threads
//                (one per gate g), NB=4 batch rows/block, W_hh row in VGPRs.

#define TT 512
#define BB 512
#define II 100
#define HH 96
#define GG 288   // 3*H
#define NB 4     // batch rows per scan block

__device__ __forceinline__ float fast_rcp(float x) { return __builtin_amdgcn_rcpf(x); }
__device__ __forceinline__ float sigmoidf_(float x) { return fast_rcp(1.f + __expf(-x)); }
__device__ __forceinline__ float tanhf_(float x) {
    float e = __expf(-2.f * x);
    return (1.f - e) * fast_rcp(1.f + e);
}

// ---------------- input projection ----------------
// grid: (T*B/256, 2), block: 288. Thread g keeps W_ih[g][0..99] in regs.
__global__ __launch_bounds__(288) void proj_kernel(
    const float* __restrict__ x,
    const float* __restrict__ wih_f, const float* __restrict__ bih_f,
    const float* __restrict__ wih_b, const float* __restrict__ bih_b,
    __half* __restrict__ xp)
{
    const int dir = blockIdx.y;
    const int g = threadIdx.x;
    const float* w_ih = dir ? wih_b : wih_f;
    const float* b_ih = dir ? bih_b : bih_f;

    float w[II];
#pragma unroll
    for (int k = 0; k < II; ++k) w[k] = w_ih[g * II + k];
    const float bias = b_ih[g];

    __shared__ float xs[64 * II];  // 25.6 KB, rows 400B -> 16B aligned
    __half* out = xp + (size_t)dir * (size_t)(TT * BB) * GG;
    const int m0 = blockIdx.x * 256;

    for (int sub = 0; sub < 4; ++sub) {
        const int mbase = m0 + sub * 64;
        __syncthreads();
        const float* src = x + (size_t)mbase * II;
        for (int idx = threadIdx.x; idx < 64 * II; idx += 288) xs[idx] = src[idx];
        __syncthreads();
        for (int mm = 0; mm < 64; ++mm) {
            const float4* xr = (const float4*)(xs + mm * II);
            float acc = bias;
#pragma unroll
            for (int k4 = 0; k4 < II / 4; ++k4) {
                float4 xv = xr[k4];  // broadcast read (same addr all lanes)
                acc += xv.x * w[4 * k4 + 0];
                acc += xv.y * w[4 * k4 + 1];
                acc += xv.z * w[4 * k4 + 2];
                acc += xv.w * w[4 * k4 + 3];
            }
            const int m = mbase + mm;
            size_t mo;
            if (dir == 0) {
                mo = (size_t)m;
            } else {
                const int t = m / BB;
                const int b = m - t * BB;
                mo = (size_t)(TT - 1 - t) * BB + b;  // time-reversed storage
            }
            out[mo * GG + g] = __float2half(acc);
        }
    }
}

// ---------------- recurrent scan ----------------
// grid: (B/NB, 2), block: 288. Thread g owns gate output g for NB rows;
// W_hh[g][0..95] in regs; h state in LDS (broadcast float4 reads).
__global__ __launch_bounds__(288) void scan_kernel(
    const __half* __restrict__ xp,
    const float* __restrict__ whh_f, const float* __restrict__ bhh_f,
    const float* __restrict__ whh_b, const float* __restrict__ bhh_b,
    float* __restrict__ out)
{
    const int dir = blockIdx.y;
    const int g = threadIdx.x;
    const int b0 = blockIdx.x * NB;
    const float* w_hh = dir ? whh_b : whh_f;
    const float* b_hh = dir ? bhh_b : bhh_f;

    float w[HH];
#pragma unroll
    for (int k = 0; k < HH; ++k) w[k] = w_hh[g * HH + k];
    const float bias = b_hh[g];

    __shared__ float h[NB][HH];
    __shared__ float rb[NB][HH];
    __shared__ float zb[NB][HH];

    for (int i = threadIdx.x; i < NB * HH; i += 288) ((float*)h)[i] = 0.f;
    __syncthreads();

    const __half* xpd = xp + (size_t)dir * (size_t)(TT * BB) * GG;
    const int cls = g / HH;   // 0=r, 1=z, 2=n
    const int j = g - cls * HH;

    // prefetch xp for t=0
    __half xpc[NB], xpn[NB];
#pragma unroll
    for (int b = 0; b < NB; ++b)
        xpc[b] = xpd[((size_t)0 * BB + b0 + b) * GG + g];

    for (int t = 0; t < TT; ++t) {
        // issue next step's xp loads early (hide HBM latency under the dot)
        if (t + 1 < TT) {
            const size_t nrow = ((size_t)(t + 1) * BB + b0) * GG;
#pragma unroll
            for (int b = 0; b < NB; ++b) xpn[b] = xpd[nrow + (size_t)b * GG + g];
        }

        float hp[NB];
#pragma unroll
        for (int b = 0; b < NB; ++b) {
            float acc = bias;
            const float4* hr = (const float4*)h[b];
#pragma unroll
            for (int k4 = 0; k4 < HH / 4; ++k4) {
                float4 hv = hr[k4];  // broadcast
                acc += hv.x * w[4 * k4 + 0];
                acc += hv.y * w[4 * k4 + 1];
                acc += hv.z * w[4 * k4 + 2];
                acc += hv.w * w[4 * k4 + 3];
            }
            hp[b] = acc;
        }

        if (cls == 0) {
#pragma unroll
            for (int b = 0; b < NB; ++b)
                rb[b][j] = sigmoidf_(__half2float(xpc[b]) + hp[b]);
        } else if (cls == 1) {
#pragma unroll
            for (int b = 0; b < NB; ++b)
                zb[b][j] = sigmoidf_(__half2float(xpc[b]) + hp[b]);
        }
        __syncthreads();  // r,z visible; all h reads of this step done

        if (cls == 2) {
            const int orow = (dir == 0) ? t : (TT - 1 - t);
#pragma unroll
            for (int b = 0; b < NB; ++b) {
                const float r = rb[b][j];
                const float z = zb[b][j];
                const float n = tanhf_(__half2float(xpc[b]) + r * hp[b]);
                const float hn = (1.f - z) * n + z * h[b][j];
                h[b][j] = hn;
                out[((size_t)orow * BB + (b0 + b)) * (2 * HH) + dir * HH + j] = hn;
            }
        }
        __syncthreads();  // h update visible before next step

#pragma unroll
        for (int b = 0; b < NB; ++b) xpc[b] = xpn[b];
    }
}

__global__ void sentinel_kernel(float* out) {
    if (threadIdx.x == 0 && blockIdx.x == 0) out[0] = 1e9f;  // ws too small marker
}

extern "C" void kernel_launch(void* const* d_in, const int* in_sizes, int n_in,
                              void* d_out, int out_size, void* d_ws, size_t ws_size,
                              hipStream_t stream)
{
    const float* x     = (const float*)d_in[0];
    const float* wih_f = (const float*)d_in[1];
    const float* whh_f = (const float*)d_in[2];
    const float* bih_f = (const float*)d_in[3];
    const float* bhh_f = (const float*)d_in[4];
    const float* wih_b = (const float*)d_in[5];
    const float* whh_b = (const float*)d_in[6];
    const float* bih_b = (const float*)d_in[7];
    const float* bhh_b = (const float*)d_in[8];
    float* out = (float*)d_out;

    const size_t ws_needed = (size_t)2 * TT * BB * GG * sizeof(__half);  // ~302 MB
    if (ws_size < ws_needed) {
        sentinel_kernel<<<1, 64, 0, stream>>>(out);
        return;
    }
    __half* xp = (__half*)d_ws;

    dim3 pgrid(TT * BB / 256, 2);
    proj_kernel<<<pgrid, 288, 0, stream>>>(x, wih_f, bih_f, wih_b, bih_b, xp);

    dim3 sgrid(BB / NB, 2);
    scan_kernel<<<sgrid, 288, 0, stream>>>(xp, whh_f, bhh_f, whh_b, bhh_b, out);
}